// Round 1
// baseline (205.768 us; speedup 1.0000x reference)
//
#include <hip/hip_runtime.h>

// Problem constants (from reference): B=8, N=128, D=256, C=3
#define BB 8
#define NN 128
#define DD 256
#define NF4 (DD / 4)   // 64 float4 per (b,n,m) row

// Kernel 1: compute per-(b,n) weight w[b,n] = lam[b,n] / num_node[b]^2
// and zero d_out. 8 blocks x 128 threads (thread = n index).
__global__ __launch_bounds__(128) void prep_kernel(
    const float* __restrict__ se_score,   // (B,3,N)
    const int*   __restrict__ sub_graph,  // (B,)
    const float* __restrict__ num_node,   // (B,)
    float* __restrict__ wbuf,             // (B,N) out
    float* __restrict__ out)              // (B,1,D) zeroed here
{
    const int b = blockIdx.x;
    const int t = threadIdx.x;   // n in [0,128)

    const float s0 = se_score[b * 3 * NN + t];
    const float s1 = se_score[b * 3 * NN + NN + t];
    const float sc = s0 + s1;

    // lam_b = sum over all 2*N entries of score2 + 1e-6
    float r = sc;
    #pragma unroll
    for (int off = 32; off > 0; off >>= 1)
        r += __shfl_down(r, off, 64);
    __shared__ float wpart[2];
    if ((t & 63) == 0) wpart[t >> 6] = r;
    __syncthreads();
    const float lam_b = wpart[0] + wpart[1] + 1e-6f;

    // sub_graph one-hot masked by zero_one_hot (column 0 forced to 0)
    const float mask = (sub_graph[b] == t && t != 0) ? 1.0f : 0.0f;
    const float nn = num_node[b];

    wbuf[b * NN + t] = (sc + mask) / (lam_b * nn * nn);

    // zero the output (harness poisons it to 0xAA before every launch)
    out[b * DD + t] = 0.0f;
    out[b * DD + NN + t] = 0.0f;
}

// Kernel 2: one block per (b,n). Stream s_e[b,n,:,:] (128x256 fp32 = 128 KB,
// contiguous), reduce over m, fuse 128*s_v term and weight, atomicAdd into out.
__global__ __launch_bounds__(256) void reduce_kernel(
    const float4* __restrict__ se4,   // (B,N,N,D) as float4
    const float4* __restrict__ sv4,   // (B,N,D)   as float4
    const float*  __restrict__ wbuf,  // (B,N)
    float* __restrict__ out)          // (B,D), pre-zeroed
{
    const int blk = blockIdx.x;      // 0..1023
    const int b   = blk >> 7;
    const int n   = blk & 127;
    const int tid = threadIdx.x;     // 0..255
    const int v   = tid & 63;        // float4 column (d/4)
    const int s   = tid >> 6;        // m-slice 0..3

    const float4* __restrict__ p = se4 + (size_t)(b * NN + n) * (NN * NF4);

    float4 a0 = make_float4(0.f, 0.f, 0.f, 0.f);
    float4 a1 = make_float4(0.f, 0.f, 0.f, 0.f);
    #pragma unroll 4
    for (int m = s; m < NN; m += 8) {
        const float4 x = p[m * NF4 + v];
        const float4 y = p[(m + 4) * NF4 + v];
        a0.x += x.x; a0.y += x.y; a0.z += x.z; a0.w += x.w;
        a1.x += y.x; a1.y += y.y; a1.z += y.z; a1.w += y.w;
    }
    float4 a;
    a.x = a0.x + a1.x; a.y = a0.y + a1.y;
    a.z = a0.z + a1.z; a.w = a0.w + a1.w;

    __shared__ float4 sm[256];
    sm[tid] = a;
    __syncthreads();

    if (tid < 64) {
        const float4 t0 = sm[tid];
        const float4 t1 = sm[tid + 64];
        const float4 t2 = sm[tid + 128];
        const float4 t3 = sm[tid + 192];
        const float  w  = wbuf[b * NN + n];
        const float4 sv = sv4[(size_t)(b * NN + n) * NF4 + v];

        const float rx = w * (128.0f * sv.x + t0.x + t1.x + t2.x + t3.x);
        const float ry = w * (128.0f * sv.y + t0.y + t1.y + t2.y + t3.y);
        const float rz = w * (128.0f * sv.z + t0.z + t1.z + t2.z + t3.z);
        const float rw = w * (128.0f * sv.w + t0.w + t1.w + t2.w + t3.w);

        float* o = out + b * DD + v * 4;
        atomicAdd(o + 0, rx);
        atomicAdd(o + 1, ry);
        atomicAdd(o + 2, rz);
        atomicAdd(o + 3, rw);
    }
}

extern "C" void kernel_launch(void* const* d_in, const int* in_sizes, int n_in,
                              void* d_out, int out_size, void* d_ws, size_t ws_size,
                              hipStream_t stream) {
    const float* s_v       = (const float*)d_in[0];  // (B,N,D)
    const float* s_e       = (const float*)d_in[1];  // (B,N,N,D)
    const int*   sub_graph = (const int*)  d_in[2];  // (B,)
    const float* s_e_score = (const float*)d_in[3];  // (B,3,N)
    const float* num_node  = (const float*)d_in[4];  // (B,)
    float* out  = (float*)d_out;                     // (B,1,D) fp32
    float* wbuf = (float*)d_ws;                      // B*N floats = 4 KB

    prep_kernel<<<BB, NN, 0, stream>>>(s_e_score, sub_graph, num_node, wbuf, out);
    reduce_kernel<<<BB * NN, 256, 0, stream>>>(
        (const float4*)s_e, (const float4*)s_v, wbuf, out);
}

// Round 2
// 200.733 us; speedup vs baseline: 1.0251x; 1.0251x over previous
//
#include <hip/hip_runtime.h>

// Problem constants (from reference): B=8, N=128, D=256, C=3
#define BB 8
#define NN 128
#define DD 256
#define NF4 (DD / 4)   // 64 float4 per (b,n,m) row

// Pass 1: one block per (b,n). Computes w[b,n] inline (block-reduce of the
// 2N score entries, all L2-hot), streams s_e[b,n,:,:] (128 KB contiguous)
// with float4 loads, reduces over m, fuses the N*s_v term and weight, and
// writes the 1 KB weighted partial r[b,n,:] to d_ws (coalesced float4).
__global__ __launch_bounds__(256) void pass1_kernel(
    const float4* __restrict__ se4,       // (B,N,N,D) as float4
    const float4* __restrict__ sv4,       // (B,N,D)   as float4
    const float*  __restrict__ se_score,  // (B,3,N)
    const int*    __restrict__ sub_graph, // (B,)
    const float*  __restrict__ num_node,  // (B,)
    float4* __restrict__ ws4)             // (B,N,D) partials as float4
{
    const int blk = blockIdx.x;      // 0..1023
    const int b   = blk >> 7;
    const int n   = blk & 127;
    const int tid = threadIdx.x;     // 0..255
    const int v   = tid & 63;        // float4 column (d/4)
    const int s   = tid >> 6;        // m-slice / wave id 0..3

    // ---- inline lam_b: sum of score2 = se_score[b, 0:2, :] (2N = 256 vals)
    __shared__ float red[4];
    {
        float x = se_score[b * 3 * NN + tid];     // tid < 2*NN
        #pragma unroll
        for (int off = 32; off > 0; off >>= 1)
            x += __shfl_down(x, off, 64);
        if ((tid & 63) == 0) red[tid >> 6] = x;
    }
    __syncthreads();
    const float lam_b = red[0] + red[1] + red[2] + red[3] + 1e-6f;

    // ---- main stream: reduce s_e[b,n,:,:] over m
    const float4* __restrict__ p = se4 + (size_t)(b * NN + n) * (NN * NF4);

    float4 a0 = make_float4(0.f, 0.f, 0.f, 0.f);
    float4 a1 = make_float4(0.f, 0.f, 0.f, 0.f);
    #pragma unroll 4
    for (int m = s; m < NN; m += 8) {
        const float4 x = p[m * NF4 + v];
        const float4 y = p[(m + 4) * NF4 + v];
        a0.x += x.x; a0.y += x.y; a0.z += x.z; a0.w += x.w;
        a1.x += y.x; a1.y += y.y; a1.z += y.z; a1.w += y.w;
    }
    float4 a;
    a.x = a0.x + a1.x; a.y = a0.y + a1.y;
    a.z = a0.z + a1.z; a.w = a0.w + a1.w;

    __shared__ float4 sm[256];
    sm[tid] = a;
    __syncthreads();

    if (tid < 64) {
        const float4 t0 = sm[tid];
        const float4 t1 = sm[tid + 64];
        const float4 t2 = sm[tid + 128];
        const float4 t3 = sm[tid + 192];

        // per-(b,n) weight (wave-uniform; broadcast loads, L2-hot)
        const float sc   = se_score[b * 3 * NN + n] + se_score[b * 3 * NN + NN + n];
        const float mask = (sub_graph[b] == n && n != 0) ? 1.0f : 0.0f;
        const float nnum = num_node[b];
        const float w    = (sc + mask) / (lam_b * nnum * nnum);

        const float4 sv = sv4[(size_t)(b * NN + n) * NF4 + v];

        float4 r;
        r.x = w * (128.0f * sv.x + t0.x + t1.x + t2.x + t3.x);
        r.y = w * (128.0f * sv.y + t0.y + t1.y + t2.y + t3.y);
        r.z = w * (128.0f * sv.z + t0.z + t1.z + t2.z + t3.z);
        r.w = w * (128.0f * sv.w + t0.w + t1.w + t2.w + t3.w);

        ws4[(size_t)(b * NN + n) * NF4 + v] = r;   // coalesced 1 KB store
    }
}

// Pass 2: out[b,d] = sum_n ws[b,n,d]. 8 blocks x 256 threads.
// tid = part(4) x float4-col(64): each thread sums 32 n-rows of one float4
// column, LDS-combines the 4 parts, 64 threads store float4 to out.
__global__ __launch_bounds__(256) void pass2_kernel(
    const float4* __restrict__ ws4,   // (B,N,D) as float4
    float4* __restrict__ out4)        // (B,D) as float4
{
    const int b    = blockIdx.x;
    const int tid  = threadIdx.x;
    const int v    = tid & 63;
    const int part = tid >> 6;        // 0..3

    const float4* __restrict__ p = ws4 + (size_t)b * NN * NF4;

    float4 a = make_float4(0.f, 0.f, 0.f, 0.f);
    #pragma unroll 8
    for (int n = part * 32; n < part * 32 + 32; ++n) {
        const float4 x = p[n * NF4 + v];
        a.x += x.x; a.y += x.y; a.z += x.z; a.w += x.w;
    }

    __shared__ float4 sm[256];
    sm[tid] = a;
    __syncthreads();

    if (tid < 64) {
        const float4 t0 = sm[tid];
        const float4 t1 = sm[tid + 64];
        const float4 t2 = sm[tid + 128];
        const float4 t3 = sm[tid + 192];
        float4 r;
        r.x = t0.x + t1.x + t2.x + t3.x;
        r.y = t0.y + t1.y + t2.y + t3.y;
        r.z = t0.z + t1.z + t2.z + t3.z;
        r.w = t0.w + t1.w + t2.w + t3.w;
        out4[b * NF4 + v] = r;
    }
}

extern "C" void kernel_launch(void* const* d_in, const int* in_sizes, int n_in,
                              void* d_out, int out_size, void* d_ws, size_t ws_size,
                              hipStream_t stream) {
    const float* s_v       = (const float*)d_in[0];  // (B,N,D)
    const float* s_e       = (const float*)d_in[1];  // (B,N,N,D)
    const int*   sub_graph = (const int*)  d_in[2];  // (B,)
    const float* s_e_score = (const float*)d_in[3];  // (B,3,N)
    const float* num_node  = (const float*)d_in[4];  // (B,)
    float4* out4 = (float4*)d_out;                   // (B,1,D) fp32
    float4* ws4  = (float4*)d_ws;                    // B*N*D floats = 1 MB

    pass1_kernel<<<BB * NN, 256, 0, stream>>>(
        (const float4*)s_e, (const float4*)s_v, s_e_score, sub_graph, num_node, ws4);
    pass2_kernel<<<BB, 256, 0, stream>>>(ws4, out4);
}